// Round 13
// baseline (652.640 us; speedup 1.0000x reference)
//
#include <hip/hip_runtime.h>

#define HDIM 64

__device__ __forceinline__ float fast_sigmoid(float v) {
    return __builtin_amdgcn_rcpf(1.0f + __builtin_amdgcn_exp2f(-1.442695041f * v));
}

__device__ __forceinline__ float fast_tanh(float v) {
    return 1.0f - 2.0f * __builtin_amdgcn_rcpf(1.0f + __builtin_amdgcn_exp2f(2.885390082f * v));
}

__device__ __forceinline__ float readlane_f(float v, int k) {
    return __uint_as_float((unsigned)__builtin_amdgcn_readlane((int)__float_as_uint(v), k));
}

// GATE-SPLIT: 256 threads = 4 waves per batch element (512 blocks).
// Wave g owns gate g (PyTorch order i,f,g,o) for ALL 64 units; lane l holds
// the full K=64 recurrent row (g*64+l): 64 weights/lane pinned in VGPRs
// (the proven-resident budget).
//  - dot product is LANE-LOCAL: no cross-lane reduce at all.
//  - h is broadcast via 64 unrolled v_readlane into wave-uniform regs
//    (scalar operand of v_fmac) -> h NEVER goes through LDS: no h ds_reads,
//    no h ds_write, none of the old reduce round-trips.
//  - per step: 1 broadcast x b128 read, 1 act b32 write, 1 barrier,
//    1 act b128 read (8-way conflict, cheap), cell update (redundant,
//    bitwise-identical across waves), 64 readlanes.
// x staged through LDS per 64-step chunk (global loads drain once per chunk).
__global__ __launch_bounds__(256)
__attribute__((amdgpu_waves_per_eu(2, 2)))
void bilstm_kernel(const float* __restrict__ x,
                   const float* __restrict__ w_ih_f,
                   const float* __restrict__ w_hh_f,
                   const float* __restrict__ b_ih_f,
                   const float* __restrict__ b_hh_f,
                   const float* __restrict__ w_ih_b,
                   const float* __restrict__ b_ih_b,
                   const float* __restrict__ b_hh_b,
                   const float* __restrict__ w_fc,
                   const float* __restrict__ b_fc,
                   float* __restrict__ out,
                   int T)
{
    const int b   = blockIdx.x;
    const int tid = threadIdx.x;
    const int g   = tid >> 6;        // gate id 0..3 (i,f,g,o)
    const int l   = tid & 63;        // unit index
    const int r   = (g << 6) | l;    // weight row

    __shared__ __align__(16) float abuf[2][HDIM][4];   // [parity][unit][gate]
    __shared__ __align__(16) float xstage[2][64][4];   // [parity][step][comp]

    // ---- per-lane weights: full K=64 row of gate g, unit l ----
    float wreg[HDIM];
    {
        const float* row = w_hh_f + (size_t)r * HDIM;
        #pragma unroll
        for (int q = 0; q < 16; ++q) {
            float4 v = *(const float4*)(row + 4 * q);
            wreg[4 * q + 0] = v.x;
            wreg[4 * q + 1] = v.y;
            wreg[4 * q + 2] = v.z;
            wreg[4 * q + 3] = v.w;
        }
    }
    // Pin: forbid rematerialization inside the t-loop.
    #pragma unroll
    for (int q = 0; q < 8; ++q) {
        asm volatile("" : "+v"(wreg[8*q+0]), "+v"(wreg[8*q+1]),
                          "+v"(wreg[8*q+2]), "+v"(wreg[8*q+3]),
                          "+v"(wreg[8*q+4]), "+v"(wreg[8*q+5]),
                          "+v"(wreg[8*q+6]), "+v"(wreg[8*q+7]));
    }

    float4 wx = *(const float4*)(w_ih_f + (size_t)r * 4);
    float  bz = b_ih_f[r] + b_hh_f[r];
    asm volatile("" : "+v"(wx.x), "+v"(wx.y), "+v"(wx.z), "+v"(wx.w), "+v"(bz));

    // activation selector (wave-uniform): sigmoid for g!=2, tanh for g==2
    const float sc = (g == 2) ? 2.885390082f : -1.442695041f;

    const float* xb = x + (size_t)b * T * 4;
    const int lim = T * 4 - 1;

    // prologue: stage chunk 0
    {
        int idx = tid;  if (idx > lim) idx = lim;
        xstage[0][tid >> 2][tid & 3] = xb[idx];
    }
    __syncthreads();

    // h broadcast registers (wave-uniform after readlane) + cell state
    float hs[HDIM];
    #pragma unroll
    for (int k = 0; k < HDIM; ++k) hs[k] = 0.0f;
    float c = 0.0f, h = 0.0f;

    const int NCH = (T + 63) >> 6;

    for (int ch = 0; ch < NCH; ++ch) {
        const int nst = ((T - (ch << 6)) < 64) ? (T - (ch << 6)) : 64;
        const float (*xs)[4] = xstage[ch & 1];
        const bool more = (ch + 1 < NCH);
        float xnf = 0.0f;
        if (more) {
            int idx = ((ch + 1) << 8) + tid;  if (idx > lim) idx = lim;
            xnf = xb[idx];   // drained once per chunk at a barrier, not per step
        }

        #define STEP(S, P) do {                                              \
            const float4 xt = *(const float4*)xs[S];   /* broadcast read */  \
            float a0 = bz, a1 = 0.0f, a2 = 0.0f, a3 = 0.0f;                  \
            _Pragma("unroll")                                                \
            for (int q = 0; q < 16; ++q) {                                   \
                a0 += wreg[4*q + 0] * hs[4*q + 0];                           \
                a1 += wreg[4*q + 1] * hs[4*q + 1];                           \
                a2 += wreg[4*q + 2] * hs[4*q + 2];                           \
                a3 += wreg[4*q + 3] * hs[4*q + 3];                           \
            }                                                                \
            a0 += wx.x * xt.x; a1 += wx.y * xt.y;                            \
            a2 += wx.z * xt.z; a3 += wx.w * xt.w;                            \
            const float A = (a0 + a1) + (a2 + a3);                           \
            const float e = __builtin_amdgcn_exp2f(sc * A);                  \
            const float rr = __builtin_amdgcn_rcpf(1.0f + e);                \
            const float v = (g == 2) ? 1.0f - 2.0f * rr : rr;                \
            abuf[P][l][g] = v;                                               \
            __syncthreads();                                                 \
            const float4 g4 = *(const float4*)abuf[P][l];                    \
            c = g4.y * c + g4.x * g4.z;                                      \
            h = g4.w * fast_tanh(c);                                         \
            _Pragma("unroll")                                                \
            for (int k = 0; k < HDIM; ++k) hs[k] = readlane_f(h, k);         \
        } while (0)

        for (int s = 0; s < nst; s += 2) {
            STEP(s,     0);
            STEP(s + 1, 1);
        }
        #undef STEP

        if (more) {
            xstage[(ch + 1) & 1][tid >> 2][tid & 3] = xnf;
            __syncthreads();
        }
    }

    // ---- epilogue: wave 0 handles backward cell + fc + sigmoid ----
    if (g == 0) {
        // backward-direction single cell from zero state at x[:, T-1]
        // (w_hh_b never multiplies nonzero state)
        float4 xl = *(const float4*)(xb + 4 * (T - 1));
        float gb[4];
        #pragma unroll
        for (int jj = 0; jj < 4; ++jj) {
            const int rr2 = (jj << 6) | l;
            float4 wb = *(const float4*)(w_ih_b + (size_t)rr2 * 4);
            gb[jj] = b_ih_b[rr2] + b_hh_b[rr2]
                   + wb.x * xl.x + wb.y * xl.y + wb.z * xl.z + wb.w * xl.w;
        }
        const float ib  = fast_sigmoid(gb[0]);
        const float ggv = fast_tanh(gb[2]);
        const float ob  = fast_sigmoid(gb[3]);
        const float cb  = ib * ggv;
        const float hbk = ob * fast_tanh(cb);

        // h register holds the final forward h for unit l
        float p = w_fc[l] * h + w_fc[HDIM + l] * hbk;
        #pragma unroll
        for (int off = 32; off; off >>= 1) p += __shfl_xor(p, off);

        if (l == 0) out[b] = fast_sigmoid(p + b_fc[0]);
    }
}

extern "C" void kernel_launch(void* const* d_in, const int* in_sizes, int n_in,
                              void* d_out, int out_size, void* d_ws, size_t ws_size,
                              hipStream_t stream) {
    const float* x      = (const float*)d_in[0];
    const float* w_ih_f = (const float*)d_in[1];
    const float* w_hh_f = (const float*)d_in[2];
    const float* b_ih_f = (const float*)d_in[3];
    const float* b_hh_f = (const float*)d_in[4];
    const float* w_ih_b = (const float*)d_in[5];
    // d_in[6] = w_hh_b — unused (backward cell starts from zero state)
    const float* b_ih_b = (const float*)d_in[7];
    const float* b_hh_b = (const float*)d_in[8];
    const float* w_fc   = (const float*)d_in[9];
    const float* b_fc   = (const float*)d_in[10];
    float* out = (float*)d_out;

    const int B = out_size;                 // 512
    const int T = in_sizes[0] / (B * 4);    // 1000

    bilstm_kernel<<<dim3(B), dim3(256), 0, stream>>>(
        x, w_ih_f, w_hh_f, b_ih_f, b_hh_f,
        w_ih_b, b_ih_b, b_hh_b, w_fc, b_fc, out, T);
}

// Round 14
// 503.006 us; speedup vs baseline: 1.2975x; 1.2975x over previous
//
#include <hip/hip_runtime.h>

#define HDIM 64

__device__ __forceinline__ float fast_sigmoid(float v) {
    return __builtin_amdgcn_rcpf(1.0f + __builtin_amdgcn_exp2f(-1.442695041f * v));
}

__device__ __forceinline__ float fast_tanh(float v) {
    return 1.0f - 2.0f * __builtin_amdgcn_rcpf(1.0f + __builtin_amdgcn_exp2f(2.885390082f * v));
}

// 256 threads = 4 waves per batch element.  (Round-6 champion, restored.)
// lane l of wave w:  j = l>>4 (k-slice group), i = l&15, output m = w*16+i.
// Lane holds weights for ALL 4 gates of output m over k in [16j,16j+16):
//   64 floats pinned in VGPRs (the empirically maximal register-resident set).
// x staged through LDS in 64-step chunks (no per-step global loads -> the
// compiler's vmcnt(0)-drain-before-barrier fires once per chunk, not per
// step). Butterfly reduce via 2 shfl_xor levels; one barrier per step.
// Seven structural variants (r7-r13) all measured slower; this is the
// latency-bound floor for the LDS-synchronized f32 recurrence.
__global__ __launch_bounds__(256)
__attribute__((amdgpu_waves_per_eu(2, 2)))
void bilstm_kernel(const float* __restrict__ x,
                   const float* __restrict__ w_ih_f,
                   const float* __restrict__ w_hh_f,
                   const float* __restrict__ b_ih_f,
                   const float* __restrict__ b_hh_f,
                   const float* __restrict__ w_ih_b,
                   const float* __restrict__ b_ih_b,
                   const float* __restrict__ b_hh_b,
                   const float* __restrict__ w_fc,
                   const float* __restrict__ b_fc,
                   float* __restrict__ out,
                   int T)
{
    const int b   = blockIdx.x;
    const int tid = threadIdx.x;
    const int w   = tid >> 6;        // wave 0..3
    const int l   = tid & 63;        // lane 0..63
    const int j   = l >> 4;          // k-slice group 0..3
    const int i   = l & 15;
    const int m   = (w << 4) | i;    // output index 0..63

    __shared__ float hbuf[2][HDIM];
    __shared__ float xstage[2][256];   // 64 timesteps x 4 floats, double-buffered

    // ---- per-lane weights: 4 gates x k-slice [16j,16j+16) ----
    float4 wv[4][4];
    float  wx[4], bz[4];
    #pragma unroll
    for (int g = 0; g < 4; ++g) {
        const int r = (g << 6) | m;
        const float* row = w_hh_f + (size_t)r * HDIM + (j << 4);
        #pragma unroll
        for (int q = 0; q < 4; ++q) wv[g][q] = ((const float4*)row)[q];
        wx[g] = w_ih_f[(size_t)r * 4 + j];                  // x-weight, component j
        bz[g] = (j == 0) ? (b_ih_f[r] + b_hh_f[r]) : 0.0f;  // bias seeded once
    }
    // Pin weights: forbid rematerialization inside the t-loop.
    #pragma unroll
    for (int g = 0; g < 4; ++g) {
        #pragma unroll
        for (int q = 0; q < 4; ++q)
            asm volatile("" : "+v"(wv[g][q].x), "+v"(wv[g][q].y),
                              "+v"(wv[g][q].z), "+v"(wv[g][q].w));
    }
    asm volatile("" : "+v"(wx[0]), "+v"(wx[1]), "+v"(wx[2]), "+v"(wx[3]));
    asm volatile("" : "+v"(bz[0]), "+v"(bz[1]), "+v"(bz[2]), "+v"(bz[3]));

    const float* xb = x + (size_t)b * T * 4;
    const int lim = T * 4 - 1;

    // prologue: stage chunk 0, zero h
    {
        int idx = tid;  if (idx > lim) idx = lim;
        xstage[0][tid] = xb[idx];
    }
    if (tid < HDIM) hbuf[0][tid] = 0.0f;
    __syncthreads();

    float c = 0.0f, h = 0.0f;
    const int NCH = (T + 63) >> 6;   // chunks of 64 timesteps

    for (int ch = 0; ch < NCH; ++ch) {
        const int nst = ((T - (ch << 6)) < 64) ? (T - (ch << 6)) : 64;
        const float* xs = xstage[ch & 1];
        const bool more = (ch + 1 < NCH);
        float xnf = 0.0f;
        if (more) {
            int idx = ((ch + 1) << 8) + tid;  if (idx > lim) idx = lim;
            xnf = xb[idx];   // drained at first in-chunk barrier: exposed once / 64 steps
        }

        #define ACCP(HV, Q)                                               \
            p0 += wv[0][Q].x * HV.x; p0 += wv[0][Q].y * HV.y;             \
            p0 += wv[0][Q].z * HV.z; p0 += wv[0][Q].w * HV.w;             \
            p1 += wv[1][Q].x * HV.x; p1 += wv[1][Q].y * HV.y;             \
            p1 += wv[1][Q].z * HV.z; p1 += wv[1][Q].w * HV.w;             \
            p2 += wv[2][Q].x * HV.x; p2 += wv[2][Q].y * HV.y;             \
            p2 += wv[2][Q].z * HV.z; p2 += wv[2][Q].w * HV.w;             \
            p3 += wv[3][Q].x * HV.x; p3 += wv[3][Q].y * HV.y;             \
            p3 += wv[3][Q].z * HV.z; p3 += wv[3][Q].w * HV.w;
        #define ACCQ(HV, Q)                                               \
            q0 += wv[0][Q].x * HV.x; q0 += wv[0][Q].y * HV.y;             \
            q0 += wv[0][Q].z * HV.z; q0 += wv[0][Q].w * HV.w;             \
            q1 += wv[1][Q].x * HV.x; q1 += wv[1][Q].y * HV.y;             \
            q1 += wv[1][Q].z * HV.z; q1 += wv[1][Q].w * HV.w;             \
            q2 += wv[2][Q].x * HV.x; q2 += wv[2][Q].y * HV.y;             \
            q2 += wv[2][Q].z * HV.z; q2 += wv[2][Q].w * HV.w;             \
            q3 += wv[3][Q].x * HV.x; q3 += wv[3][Q].y * HV.y;             \
            q3 += wv[3][Q].z * HV.z; q3 += wv[3][Q].w * HV.w;

        #define STEP(S, RA, RB) do {                                       \
            const float xj = xs[((S) << 2) + j];                           \
            const float4* hp = (const float4*)(&hbuf[RA][j << 4]);         \
            float4 h0 = hp[0], h1 = hp[1], h2 = hp[2], h3 = hp[3];         \
            float p0 = bz[0] + wx[0] * xj, p1 = bz[1] + wx[1] * xj;        \
            float p2 = bz[2] + wx[2] * xj, p3 = bz[3] + wx[3] * xj;        \
            float q0 = 0.0f, q1 = 0.0f, q2 = 0.0f, q3 = 0.0f;              \
            ACCP(h0, 0) ACCQ(h1, 1) ACCP(h2, 2) ACCQ(h3, 3)                \
            p0 += q0; p1 += q1; p2 += q2; p3 += q3;                        \
            p0 += __shfl_xor(p0, 16); p1 += __shfl_xor(p1, 16);            \
            p2 += __shfl_xor(p2, 16); p3 += __shfl_xor(p3, 16);            \
            p0 += __shfl_xor(p0, 32); p1 += __shfl_xor(p1, 32);            \
            p2 += __shfl_xor(p2, 32); p3 += __shfl_xor(p3, 32);            \
            const float gi = fast_sigmoid(p0);                             \
            const float gf = fast_sigmoid(p1);                             \
            const float gg = fast_tanh(p2);                                \
            const float go = fast_sigmoid(p3);                             \
            c = gf * c + gi * gg;                                          \
            h = go * fast_tanh(c);                                         \
            if (l < 16) hbuf[RB][m] = h;                                   \
            __syncthreads();                                               \
        } while (0)

        for (int s = 0; s < nst; s += 2) {
            STEP(s,     0, 1);
            STEP(s + 1, 1, 0);
        }
        #undef STEP
        #undef ACCP
        #undef ACCQ

        if (more) {
            xstage[(ch + 1) & 1][tid] = xnf;
            __syncthreads();
        }
    }

    // ---- epilogue: wave 0 handles backward cell + fc + sigmoid ----
    if (w == 0) {
        // backward-direction single cell from zero state at x[:, T-1]
        // (w_hh_b never multiplies nonzero state)
        float4 xl = *(const float4*)(xb + 4 * (T - 1));
        float gb[4];
        #pragma unroll
        for (int jj = 0; jj < 4; ++jj) {
            const int rr2 = (jj << 6) | l;
            float4 wb = *(const float4*)(w_ih_b + (size_t)rr2 * 4);
            gb[jj] = b_ih_b[rr2] + b_hh_b[rr2]
                   + wb.x * xl.x + wb.y * xl.y + wb.z * xl.z + wb.w * xl.w;
        }
        const float ib  = fast_sigmoid(gb[0]);
        const float ggb = fast_tanh(gb[2]);
        const float ob  = fast_sigmoid(gb[3]);
        const float cb  = ib * ggb;
        const float hb  = ob * fast_tanh(cb);

        const float hf = hbuf[0][l];   // T even -> final h lands in buffer 0
        float p = w_fc[l] * hf + w_fc[HDIM + l] * hb;
        #pragma unroll
        for (int off = 32; off; off >>= 1) p += __shfl_xor(p, off);

        if (l == 0) out[b] = fast_sigmoid(p + b_fc[0]);
    }
}

extern "C" void kernel_launch(void* const* d_in, const int* in_sizes, int n_in,
                              void* d_out, int out_size, void* d_ws, size_t ws_size,
                              hipStream_t stream) {
    const float* x      = (const float*)d_in[0];
    const float* w_ih_f = (const float*)d_in[1];
    const float* w_hh_f = (const float*)d_in[2];
    const float* b_ih_f = (const float*)d_in[3];
    const float* b_hh_f = (const float*)d_in[4];
    const float* w_ih_b = (const float*)d_in[5];
    // d_in[6] = w_hh_b — unused (backward cell starts from zero state)
    const float* b_ih_b = (const float*)d_in[7];
    const float* b_hh_b = (const float*)d_in[8];
    const float* w_fc   = (const float*)d_in[9];
    const float* b_fc   = (const float*)d_in[10];
    float* out = (float*)d_out;

    const int B = out_size;                 // 512
    const int T = in_sizes[0] / (B * 4);    // 1000

    bilstm_kernel<<<dim3(B), dim3(256), 0, stream>>>(
        x, w_ih_f, w_hh_f, b_ih_f, b_hh_f,
        w_ih_b, b_ih_b, b_hh_b, w_fc, b_fc, out, T);
}

// Round 16
// 446.660 us; speedup vs baseline: 1.4612x; 1.1261x over previous
//
#include <hip/hip_runtime.h>

#define HDIM 64

typedef _Float16 h2  __attribute__((ext_vector_type(2)));   // dot2 operand type
typedef __fp16   fp2 __attribute__((ext_vector_type(2)));   // cvt_pkrtz result type

#if defined(__has_builtin)
# if __has_builtin(__builtin_amdgcn_fdot2)
#  define FDOT2(a, b, c) __builtin_amdgcn_fdot2((a), (b), (c), false)
# endif
#endif
#ifndef FDOT2
__device__ __forceinline__ float fdot2_asm(h2 a, h2 b, float c) {
    float d;
    asm("v_dot2_f32_f16 %0, %1, %2, %3" : "=v"(d) : "v"(a), "v"(b), "v"(c));
    return d;
}
# define FDOT2(a, b, c) fdot2_asm((a), (b), (c))
#endif

__device__ __forceinline__ float fast_sigmoid(float v) {
    return __builtin_amdgcn_rcpf(1.0f + __builtin_amdgcn_exp2f(-1.442695041f * v));
}

__device__ __forceinline__ float fast_tanh(float v) {
    return 1.0f - 2.0f * __builtin_amdgcn_rcpf(1.0f + __builtin_amdgcn_exp2f(2.885390082f * v));
}

// ONE WAVE per batch element (512 blocks x 64 threads), NO barriers, NO
// cross-lane reduce. Lane l owns all 4 gate rows of unit l with the full
// K=64 dot product, weights packed f16 (v_dot2_f32_f16, f32 accumulate):
// 256 weights = 128 packed VGPRs — fits the waves_per_eu(1,1) 512-reg budget
// where the f32 version (256 regs) did not (r7: allocator gave 180).
// h hand-off: lane writes h as f16 (ds_write_b16), next step reads all 64
// halves as 8 broadcast b128 — in-order DS within the wave (validated r7).
// x: per-step global prefetch; with no barriers there is no vmcnt drain.
__global__ __launch_bounds__(64)
__attribute__((amdgpu_waves_per_eu(1, 1)))
void bilstm_kernel(const float* __restrict__ x,
                   const float* __restrict__ w_ih_f,
                   const float* __restrict__ w_hh_f,
                   const float* __restrict__ b_ih_f,
                   const float* __restrict__ b_hh_f,
                   const float* __restrict__ w_ih_b,
                   const float* __restrict__ b_ih_b,
                   const float* __restrict__ b_hh_b,
                   const float* __restrict__ w_fc,
                   const float* __restrict__ b_fc,
                   float* __restrict__ out,
                   int T)
{
    const int b = blockIdx.x;
    const int l = threadIdx.x;     // unit index; owns rows {l, 64+l, 128+l, 192+l}

    __shared__ __align__(16) _Float16 hlds[HDIM];

    // ---- pack 4x64 recurrent weights into 128 h2 regs (stored as uint) ----
    unsigned wu[128];              // [g*32 + q2] = packed {w[2q2], w[2q2+1]}
    #pragma unroll
    for (int g = 0; g < 4; ++g) {
        const float* row = w_hh_f + (size_t)((g << 6) | l) * HDIM;
        #pragma unroll
        for (int q = 0; q < 16; ++q) {
            float4 v = *(const float4*)(row + 4 * q);
            fp2 p0 = __builtin_amdgcn_cvt_pkrtz(v.x, v.y);
            fp2 p1 = __builtin_amdgcn_cvt_pkrtz(v.z, v.w);
            wu[(g << 5) + 2 * q + 0] = __builtin_bit_cast(unsigned, p0);
            wu[(g << 5) + 2 * q + 1] = __builtin_bit_cast(unsigned, p1);
        }
    }
    // Pin: forbid rematerialization inside the t-loop.
    #pragma unroll
    for (int q = 0; q < 16; ++q) {
        asm volatile("" : "+v"(wu[8*q+0]), "+v"(wu[8*q+1]),
                          "+v"(wu[8*q+2]), "+v"(wu[8*q+3]),
                          "+v"(wu[8*q+4]), "+v"(wu[8*q+5]),
                          "+v"(wu[8*q+6]), "+v"(wu[8*q+7]));
    }

    float4 wx[4];
    float  bz[4];
    #pragma unroll
    for (int g = 0; g < 4; ++g) {
        const int r = (g << 6) | l;
        wx[g] = *(const float4*)(w_ih_f + (size_t)r * 4);
        bz[g] = b_ih_f[r] + b_hh_f[r];
        asm volatile("" : "+v"(wx[g].x), "+v"(wx[g].y), "+v"(wx[g].z),
                          "+v"(wx[g].w), "+v"(bz[g]));
    }

    hlds[l] = (_Float16)0.0f;      // in-order DS: visible to step-0 reads

    const float* xb = x + (size_t)b * T * 4;
    float4 xcur = *(const float4*)(xb);
    float c = 0.0f, h = 0.0f;

    #define W2(g, qq) __builtin_bit_cast(h2, wu[((g) << 5) + (qq)])
    #define H2(u)     __builtin_bit_cast(h2, (u))

    for (int t = 0; t < T; ++t) {
        const int tn = (t + 1 < T) ? t + 1 : T - 1;
        float4 xnext = *(const float4*)(xb + 4 * tn);   // no barrier -> stays in flight

        // 8 accumulator chains (2 per gate), v_dot2_f32_f16, 16 deep each
        float aA0 = bz[0], aB0 = 0.0f;
        float aA1 = bz[1], aB1 = 0.0f;
        float aA2 = bz[2], aB2 = 0.0f;
        float aA3 = bz[3], aB3 = 0.0f;

        const uint4* hp = (const uint4*)hlds;
        #pragma unroll
        for (int q = 0; q < 8; ++q) {
            const uint4 hv = hp[q];        // broadcast b128 = 8 halves
            aA0 = FDOT2(W2(0, 4*q+0), H2(hv.x), aA0);
            aB0 = FDOT2(W2(0, 4*q+1), H2(hv.y), aB0);
            aA0 = FDOT2(W2(0, 4*q+2), H2(hv.z), aA0);
            aB0 = FDOT2(W2(0, 4*q+3), H2(hv.w), aB0);
            aA1 = FDOT2(W2(1, 4*q+0), H2(hv.x), aA1);
            aB1 = FDOT2(W2(1, 4*q+1), H2(hv.y), aB1);
            aA1 = FDOT2(W2(1, 4*q+2), H2(hv.z), aA1);
            aB1 = FDOT2(W2(1, 4*q+3), H2(hv.w), aB1);
            aA2 = FDOT2(W2(2, 4*q+0), H2(hv.x), aA2);
            aB2 = FDOT2(W2(2, 4*q+1), H2(hv.y), aB2);
            aA2 = FDOT2(W2(2, 4*q+2), H2(hv.z), aA2);
            aB2 = FDOT2(W2(2, 4*q+3), H2(hv.w), aB2);
            aA3 = FDOT2(W2(3, 4*q+0), H2(hv.x), aA3);
            aB3 = FDOT2(W2(3, 4*q+1), H2(hv.y), aB3);
            aA3 = FDOT2(W2(3, 4*q+2), H2(hv.z), aA3);
            aB3 = FDOT2(W2(3, 4*q+3), H2(hv.w), aB3);
        }

        float A0 = aA0 + aB0 + (wx[0].x * xcur.x + wx[0].y * xcur.y
                              + wx[0].z * xcur.z + wx[0].w * xcur.w);
        float A1 = aA1 + aB1 + (wx[1].x * xcur.x + wx[1].y * xcur.y
                              + wx[1].z * xcur.z + wx[1].w * xcur.w);
        float A2 = aA2 + aB2 + (wx[2].x * xcur.x + wx[2].y * xcur.y
                              + wx[2].z * xcur.z + wx[2].w * xcur.w);
        float A3 = aA3 + aB3 + (wx[3].x * xcur.x + wx[3].y * xcur.y
                              + wx[3].z * xcur.z + wx[3].w * xcur.w);

        const float gi = fast_sigmoid(A0);
        const float gf = fast_sigmoid(A1);
        const float gg = fast_tanh(A2);
        const float go = fast_sigmoid(A3);
        c = gf * c + gi * gg;
        h = go * fast_tanh(c);

        hlds[l] = (_Float16)h;               // ds_write_b16; next step's reads see it
        asm volatile("" ::: "memory");       // keep program order around LDS
        xcur = xnext;
    }

    #undef W2
    #undef H2

    // ---- backward-direction cell: single step from zero state at x[:, T-1] ----
    // (w_hh_b never multiplies nonzero state; xcur == x[:, T-1] here)
    float gb[4];
    #pragma unroll
    for (int g = 0; g < 4; ++g) {
        const int r = (g << 6) | l;
        float4 wb = *(const float4*)(w_ih_b + (size_t)r * 4);
        gb[g] = b_ih_b[r] + b_hh_b[r]
              + wb.x * xcur.x + wb.y * xcur.y + wb.z * xcur.z + wb.w * xcur.w;
    }
    const float ib  = fast_sigmoid(gb[0]);
    const float ggb = fast_tanh(gb[2]);
    const float ob  = fast_sigmoid(gb[3]);
    const float cb  = ib * ggb;
    const float hb  = ob * fast_tanh(cb);

    // ---- fc + sigmoid ----
    float p = w_fc[l] * h + w_fc[HDIM + l] * hb;
    #pragma unroll
    for (int off = 32; off; off >>= 1) p += __shfl_xor(p, off);

    if (l == 0) out[b] = fast_sigmoid(p + b_fc[0]);
}

extern "C" void kernel_launch(void* const* d_in, const int* in_sizes, int n_in,
                              void* d_out, int out_size, void* d_ws, size_t ws_size,
                              hipStream_t stream) {
    const float* x      = (const float*)d_in[0];
    const float* w_ih_f = (const float*)d_in[1];
    const float* w_hh_f = (const float*)d_in[2];
    const float* b_ih_f = (const float*)d_in[3];
    const float* b_hh_f = (const float*)d_in[4];
    const float* w_ih_b = (const float*)d_in[5];
    // d_in[6] = w_hh_b — unused (backward cell starts from zero state)
    const float* b_ih_b = (const float*)d_in[7];
    const float* b_hh_b = (const float*)d_in[8];
    const float* w_fc   = (const float*)d_in[9];
    const float* b_fc   = (const float*)d_in[10];
    float* out = (float*)d_out;

    const int B = out_size;                 // 512
    const int T = in_sizes[0] / (B * 4);    // 1000

    bilstm_kernel<<<dim3(B), dim3(64), 0, stream>>>(
        x, w_ih_f, w_hh_f, b_ih_f, b_hh_f,
        w_ih_b, b_ih_b, b_hh_b, w_fc, b_fc, out, T);
}